// Round 14
// baseline (158.209 us; speedup 1.0000x reference)
//
#include <hip/hip_runtime.h>
#include <math.h>

#define B_   64
#define N_   512
#define C_   128
#define FS_  16
#define RES_ 511
#define CHUNK_ 64
#define HALO_  15
#define MAXR_  (CHUNK_ + HALO_)   // 79
#define RSTRIDE_ 132              // dwords per staged row (4*33; 16B-aligned;
                                  // addr/4 mod 8 uniform -> 2-way banking = free)

__device__ __forceinline__ float bf2f(unsigned short u) {
  union { unsigned int i; float f; } v;
  v.i = ((unsigned int)u) << 16;
  return v.f;
}

__device__ __forceinline__ float2 ld2(const void* p, int idx, int mode) {
  if (mode) return ((const float2*)p)[idx];
  ushort2 u = ((const ushort2*)p)[idx];
  return make_float2(bf2f(u.x), bf2f(u.y));
}
__device__ __forceinline__ float ld1(const void* p, int idx, int mode) {
  if (mode) return ((const float*)p)[idx];
  return bf2f(((const unsigned short*)p)[idx]);
}
__device__ __forceinline__ float4 ld4(const void* p, int idx4, int mode) {
  if (mode) return ((const float4*)p)[idx4];
  ushort4 u = ((const ushort4*)p)[idx4];
  return make_float4(bf2f(u.x), bf2f(u.y), bf2f(u.z), bf2f(u.w));
}

// wave-wide butterfly sums; identical in all 64 lanes
__device__ __forceinline__ double wred(double v) {
#pragma unroll
  for (int m = 32; m; m >>= 1) v += __shfl_xor(v, m, 64);
  return v;
}
__device__ __forceinline__ float wredf(float v) {
#pragma unroll
  for (int m = 32; m; m >>= 1) v += __shfl_xor(v, m, 64);
  return v;
}

// wave-0 parallel dtype sniff: lane i tests ushort i's exponent field.
// bf16 N(0,1): ~100% in [100,140]; f32-as-ushort: ~58%.
__device__ __forceinline__ int detect_w0(const unsigned short* p, int lane) {
  int e = (p[lane] >> 7) & 0xFF;
  unsigned long long m = __ballot(e >= 100 && e <= 140);
  return (__popcll(m) >= 48) ? 0 : 1;   // 0 = bf16 storage, 1 = f32 storage
}

__device__ __forceinline__ float get_epoch(const int* ep) {
  int ei = ep[0];
  if (ei >= 0 && ei <= 1000000) return (float)ei;
  union { int i; float f; } u; u.i = ei;
  return (u.f >= 0.f && u.f <= 1e6f) ? u.f : 10.f;
}

// ---------------- Kernel 1: fused scores + stable rank sort ---------------
// 64 blocks = one per batch (each x row read exactly once). Phase A: 8 waves
// x 64 nodes, same f64 wave-butterfly as always -> sl[] bit-identical.
// Phase B: thread t ranks node t over all 512 via float4 LDS broadcasts.
__global__ __launch_bounds__(512) void k_sortscore(
    const void* __restrict__ x, const void* __restrict__ w,
    int* __restrict__ order, float* __restrict__ srk)
{
  __shared__ __align__(16) float sl[N_];
  __shared__ int s_modes[2];
  const int b = blockIdx.x;
  const int bN = b * N_, t = threadIdx.x, lane = t & 63, wv = t >> 6;

  if (t < 64) {
    int mx_ = detect_w0((const unsigned short*)x, lane);
    int mw_ = detect_w0((const unsigned short*)w, lane);
    if (t == 0) { s_modes[0] = mx_; s_modes[1] = mw_; }
  }
  __syncthreads();
  const int mode_x = s_modes[0], mode_w = s_modes[1];

  const float2 wv2 = ld2(w, lane, mode_w);
  const double nww = wred((double)wv2.x * wv2.x + (double)wv2.y * wv2.y);
  const float nrm32 = (float)sqrt(nww);

  // phase A: wave wv computes nodes wv*64 .. wv*64+63 (once per batch)
#pragma unroll 2
  for (int i = 0; i < 64; ++i) {
    const int node = wv * 64 + i;
    float2 xv = ld2(x, (bN + node) * 64 + lane, mode_x);
    double s = wred((double)xv.x * wv2.x + (double)xv.y * wv2.y);
    if (lane == 0) sl[node] = ((float)s) / nrm32;   // f32 divide, like np
  }
  __syncthreads();

  // phase B: rank(t) = #{k: s[k]>s[t]} + #{k<t: s[k]==s[t]}  (exact, stable)
  const float my = sl[t];
  const float4* sl4 = (const float4*)sl;
  int rank = 0;
#pragma unroll 8
  for (int k4 = 0; k4 < N_ / 4; ++k4) {
    float4 v = sl4[k4];                  // LDS broadcast across the wave
    int k = k4 * 4;
    rank += (int)((v.x > my) || (v.x == my && k     < t));
    rank += (int)((v.y > my) || (v.y == my && k + 1 < t));
    rank += (int)((v.z > my) || (v.z == my && k + 2 < t));
    rank += (int)((v.w > my) || (v.w == my && k + 3 < t));
  }
  order[bN + rank] = t;
  srk[bN + rank]   = tanhf(my);
}

// ---------------- Kernel 2: LDS-staged window attention -------------------
// 512 blocks = 64 batches x 8 chunks of 64 r; 8 waves, 8 r per wave.
// asr/ads recomputed in-block from the staged rows (same f32 butterfly as
// the original k_scores -> bit-identical values).
__global__ __launch_bounds__(512) void k_att(
    const void* __restrict__ x, const void* __restrict__ a,
    const int* __restrict__ order, const int* __restrict__ ep,
    float* __restrict__ wrw, int* __restrict__ jmp)
{
  __shared__ float rows[MAXR_ * RSTRIDE_];   // 79*132*4 = 41712 B
  __shared__ float ads_l[MAXR_];
  __shared__ float asr_l[CHUNK_];
  __shared__ int   ord_l[MAXR_];
  __shared__ int   s_modes[2];
  __shared__ float s_invtau;

  const int blk = blockIdx.x;           // 64*8
  const int b = blk >> 3;
  const int cr0 = (blk & 7) * CHUNK_;
  const int bN = b * N_;
  const int t = threadIdx.x;            // 512 threads, 8 waves
  const int lane = t & 63, wv = t >> 6;
  const int nrows = min(N_ - cr0, MAXR_);

  if (t < 64) {
    int mx_ = detect_w0((const unsigned short*)x, lane);
    int ma_ = detect_w0((const unsigned short*)a, lane);
    if (t == 0) {
      s_modes[0] = mx_; s_modes[1] = ma_;
      float evv = get_epoch(ep);
      s_invtau = (float)(1.0 / (10.0 * pow(0.01, (double)evv / 100.0)));
    }
  }
  if (t < nrows) ord_l[t] = order[bN + cr0 + t];
  __syncthreads();
  const int mode_x = s_modes[0], mode_a = s_modes[1];
  const float inv_tau = s_invtau;

  // stage rows: 16 rows in flight, 32 threads x float4 per row (coalesced)
  {
    const int rl0 = t >> 5, c4 = t & 31;
    for (int rl = rl0; rl < nrows; rl += 16) {
      float4 v = ld4(x, (bN + ord_l[rl]) * 32 + c4, mode_x);
      float* dst = &rows[rl * RSTRIDE_ + c4 * 4];
      dst[0] = v.x; dst[1] = v.y; dst[2] = v.z; dst[3] = v.w;
    }
  }
  __syncthreads();

  // asr/ads from staged rows: lane covers channels 2*lane, 2*lane+1
  {
    const float2 sv2 = ld2(a, lane, mode_a);
    const float2 dv2 = ld2(a, 64 + lane, mode_a);
    for (int rl = wv; rl < nrows; rl += 8) {
      const float2 xr = *(const float2*)&rows[rl * RSTRIDE_ + 2 * lane];
      float da = wredf(xr.x * sv2.x + xr.y * sv2.y);
      float dd = wredf(xr.x * dv2.x + xr.y * dv2.y);
      if (lane == 0) {
        ads_l[rl] = dd;
        if (rl < CHUNK_) asr_l[rl] = da;
      }
    }
  }
  __syncthreads();

  const int j = lane & 15, cg4 = lane >> 4;
  const int nr = min(CHUNK_, RES_ - cr0);         // valid r in this chunk
  int cnt = nr - wv * 8; cnt = max(0, min(8, cnt));

#pragma unroll 2
  for (int ii = 0; ii < cnt; ++ii) {
    const int rloc = wv * 8 + ii;
    const int r = cr0 + rloc;
    const int dest = r + j;
    const bool valid = dest < N_;
    const int dl = (valid ? dest : (N_ - 1)) - cr0;

    const float* srcp = &rows[rloc * RSTRIDE_ + cg4 * 32];
    const float* dstp = &rows[dl   * RSTRIDE_ + cg4 * 32];
    // 4 partial f64 accumulators (dep chain 8); same order since R11.
    double p0 = 0.0, p1 = 0.0, p2 = 0.0, p3 = 0.0;
#pragma unroll
    for (int c = 0; c < 8; ++c) {
      float4 s4 = *(const float4*)(srcp + c * 4);
      float4 d4 = *(const float4*)(dstp + c * 4);
      float e0 = s4.x - d4.x, e1 = s4.y - d4.y;   // f32 subtract, like np
      float e2 = s4.z - d4.z, e3 = s4.w - d4.w;
      float q0 = e0 * e0, q1 = e1 * e1, q2 = e2 * e2, q3 = e3 * e3;
      p0 += (double)q0; p1 += (double)q1; p2 += (double)q2; p3 += (double)q3;
    }
    double dacc = (p0 + p1) + (p2 + p3);
    dacc += __shfl_xor(dacc, 16, 64);   // reduce channel quarters
    dacc += __shfl_xor(dacc, 32, 64);

    float d32 = sqrtf((float)dacc);
    float kkj = valid ? (__expf(-0.5f * d32) - 1e-20f) : -1e-20f;
    float aaj = valid ? (asr_l[rloc] + ads_l[dl]) : -1e9f;
    float ttj = aaj * inv_tau;

    float mx = ttj;
#pragma unroll
    for (int m = 1; m < 16; m <<= 1) mx = fmaxf(mx, __shfl_xor(mx, m, 64));
    float eej = __expf(ttj - mx);
    float ssum = eej;
#pragma unroll
    for (int m = 1; m < 16; m <<= 1) ssum += __shfl_xor(ssum, m, 64);
    float q  = kkj * (eej * (1.0f / ssum));
    float qm = valid ? q : -1e9f;

    float qe = (j == 0) ? -INFINITY : qm;         // exclude j=0 for jumps
    float m1 = qe;
#pragma unroll
    for (int m = 1; m < 16; m <<= 1) m1 = fmaxf(m1, __shfl_xor(m1, m, 64));
    float q0v = __shfl(qm, lane & 48, 64);        // this group's j=0 value
    float wr = fmaxf(m1, q0v);                    // == max over all j (exact)
    unsigned long long mask = __ballot(qe == m1);
    int bj = __builtin_ctz((unsigned)(mask & 0xFFFEu));   // first argmax, j>=1

    if (lane == 0) {
      wrw[bN + r] = wr;
      jmp[bN + r] = bj;
    }
  }
}

// ---------------- Kernel 3: jump-chain pooling via pointer doubling -------
__global__ __launch_bounds__(512) void k_chain(
    const void* __restrict__ x, const float* __restrict__ wrw,
    const float* __restrict__ srk, const int* __restrict__ jmp,
    const int* __restrict__ order, float* __restrict__ out)
{
  __shared__ int   tab[9][N_];   // f^(2^k) jump tables, sentinel 511
  __shared__ int   ol[N_];
  __shared__ float wl[N_];
  __shared__ float sl2[N_];
  __shared__ float cl[N_];       // coeff list in path order
  __shared__ int   rl[N_];       // row-id list
  __shared__ int   Pcnt;
  __shared__ int   s_mode;

  const int b = blockIdx.x, t = threadIdx.x;     // 512 threads
  if (t < 64) {
    int mx_ = detect_w0((const unsigned short*)x, t);
    if (t == 0) s_mode = mx_;
  }

  ol[t] = order[b * N_ + t];
  if (t < RES_) {
    wl[t]  = wrw[b * N_ + t];
    sl2[t] = srk[b * N_ + t];
    tab[0][t] = min(t + jmp[b * N_ + t], RES_);
  } else {
    tab[0][t] = RES_;
  }
  if (t == 0) Pcnt = RES_;
  __syncthreads();
  const int mode_x = s_mode;
#pragma unroll
  for (int k = 1; k < 9; ++k) {
    int v = tab[k - 1][tab[k - 1][t]];
    tab[k][t] = v;
    __syncthreads();
  }
  int node = 0;
#pragma unroll
  for (int k = 0; k < 9; ++k)
    if ((t >> k) & 1) node = tab[k][node];
  bool valid = (node < RES_);
  cl[t] = valid ? wl[node] * sl2[node] : 0.0f;
  rl[t] = valid ? ol[node] : 0;
  if (!valid) atomicMin(&Pcnt, t);
  __syncthreads();

  if (t < C_) {
    const int P = Pcnt;
    float acc = 0.f;
    int i = 0;
    for (; i + 4 <= P; i += 4) {
      float c0 = cl[i],     c1 = cl[i + 1], c2 = cl[i + 2], c3 = cl[i + 3];
      int   r0 = rl[i],     r1 = rl[i + 1], r2 = rl[i + 2], r3 = rl[i + 3];
      float x0 = ld1(x, (b * N_ + r0) * C_ + t, mode_x);
      float x1 = ld1(x, (b * N_ + r1) * C_ + t, mode_x);
      float x2 = ld1(x, (b * N_ + r2) * C_ + t, mode_x);
      float x3 = ld1(x, (b * N_ + r3) * C_ + t, mode_x);
      acc = acc + c0 * x0;                       // exact reference order
      acc = acc + c1 * x1;
      acc = acc + c2 * x2;
      acc = acc + c3 * x3;
    }
    for (; i < P; ++i)
      acc = acc + cl[i] * ld1(x, (b * N_ + rl[i]) * C_ + t, mode_x);
    out[b * C_ + t] = acc;
  }
}

extern "C" void kernel_launch(void* const* d_in, const int* in_sizes, int n_in,
                              void* d_out, int out_size, void* d_ws, size_t ws_size,
                              hipStream_t stream) {
  const void* x = nullptr; const void* w = nullptr; const void* a = nullptr;
  const int* ep = nullptr;
  for (int i = 0; i < n_in; ++i) {
    int s = in_sizes[i];
    if      (s == B_ * N_ * C_) x  = d_in[i];
    else if (s == C_)           w  = d_in[i];
    else if (s == 2 * C_)       a  = d_in[i];
    else if (s == 1)            ep = (const int*)d_in[i];
  }
  if (!x)  x  = d_in[0];
  if (!w)  w  = d_in[2];
  if (!a)  a  = d_in[3];
  if (!ep) ep = (const int*)d_in[4];
  (void)out_size; (void)ws_size;

  float* ws = (float*)d_ws;
  const int NN = B_ * N_;              // 32768
  int*   order = (int*)ws;             // NN
  float* srk   = ws + NN;              // NN
  float* wrw   = ws + 2 * NN;          // NN
  int*   jmp   = (int*)(ws + 3 * NN);  // NN

  k_sortscore<<<B_, 512, 0, stream>>>(x, w, order, srk);
  k_att<<<B_ * 8, 512, 0, stream>>>(x, a, order, ep, wrw, jmp);
  k_chain<<<B_, N_, 0, stream>>>(x, wrw, srk, jmp, order, (float*)d_out);
}

// Round 16
// 122.360 us; speedup vs baseline: 1.2930x; 1.2930x over previous
//
#include <hip/hip_runtime.h>
#include <math.h>

#define B_   64
#define N_   512
#define C_   128
#define FS_  16
#define RES_ 511
#define CHUNK_ 64
#define HALO_  15
#define MAXR_  (CHUNK_ + HALO_)   // 79
#define RSTRIDE_ 132              // dwords per staged row (4*33; 16B-aligned;
                                  // addr/4 mod 8 uniform -> 2-way banking = free)

__device__ __forceinline__ float bf2f(unsigned short u) {
  union { unsigned int i; float f; } v;
  v.i = ((unsigned int)u) << 16;
  return v.f;
}

__device__ __forceinline__ float2 ld2(const void* p, int idx, int mode) {
  if (mode) return ((const float2*)p)[idx];
  ushort2 u = ((const ushort2*)p)[idx];
  return make_float2(bf2f(u.x), bf2f(u.y));
}
__device__ __forceinline__ float ld1(const void* p, int idx, int mode) {
  if (mode) return ((const float*)p)[idx];
  return bf2f(((const unsigned short*)p)[idx]);
}
__device__ __forceinline__ float4 ld4(const void* p, int idx4, int mode) {
  if (mode) return ((const float4*)p)[idx4];
  ushort4 u = ((const ushort4*)p)[idx4];
  return make_float4(bf2f(u.x), bf2f(u.y), bf2f(u.z), bf2f(u.w));
}

// wave-wide butterfly sums; identical in all 64 lanes
__device__ __forceinline__ double wred(double v) {
#pragma unroll
  for (int m = 32; m; m >>= 1) v += __shfl_xor(v, m, 64);
  return v;
}
__device__ __forceinline__ float wredf(float v) {
#pragma unroll
  for (int m = 32; m; m >>= 1) v += __shfl_xor(v, m, 64);
  return v;
}

// wave-0 parallel dtype sniff: lane i tests ushort i's exponent field.
// bf16 N(0,1): ~100% in [100,140]; f32-as-ushort: ~58%.
__device__ __forceinline__ int detect_w0(const unsigned short* p, int lane) {
  int e = (p[lane] >> 7) & 0xFF;
  unsigned long long m = __ballot(e >= 100 && e <= 140);
  return (__popcll(m) >= 48) ? 0 : 1;   // 0 = bf16 storage, 1 = f32 storage
}

__device__ __forceinline__ float get_epoch(const int* ep) {
  int ei = ep[0];
  if (ei >= 0 && ei <= 1000000) return (float)ei;
  union { int i; float f; } u; u.i = ei;
  return (u.f >= 0.f && u.f <= 1e6f) ? u.f : 10.f;
}

// ---------------- Kernel 1: per-node score dot (one wave per node) --------
// Node-level parallelism essential (R14: 64-block fusion latency-bound at
// 5% occupancy). Score stays f64 (argsort-fragile).
__global__ __launch_bounds__(256) void k_scores(
    const void* __restrict__ x, const void* __restrict__ w,
    float* __restrict__ sc)
{
  __shared__ int s_modes[2];
  const int t = threadIdx.x, lane = t & 63;
  if (t < 64) {
    int mx_ = detect_w0((const unsigned short*)x, lane);
    int mw_ = detect_w0((const unsigned short*)w, lane);
    if (t == 0) { s_modes[0] = mx_; s_modes[1] = mw_; }
  }
  __syncthreads();
  const int mode_x = s_modes[0], mode_w = s_modes[1];
  const int wid = (blockIdx.x * blockDim.x + t) >> 6;   // node, < B_*N_

  const float2 wv2 = ld2(w, lane, mode_w);
  const double nww = wred((double)wv2.x * wv2.x + (double)wv2.y * wv2.y);
  const float nrm32 = (float)sqrt(nww);

  float2 xv = ld2(x, wid * 64 + lane, mode_x);
  double s  = wred((double)xv.x * wv2.x + (double)xv.y * wv2.y);
  if (lane == 0) sc[wid] = ((float)s) / nrm32;    // f32 divide, like np
}

// ---------------- Kernel 2: stable descending rank sort -------------------
// 512 blocks = 64 batches x 8 chunks of 64 nodes (R12-proven shape).
// rank(i) = #{k: sc[k] > sc[i]} + #{k < i: sc[k] == sc[i]}  (exact, stable)
__global__ __launch_bounds__(256) void k_sort(
    const float* __restrict__ sc, int* __restrict__ order,
    float* __restrict__ srk)
{
  __shared__ __align__(16) float sl[N_];
  __shared__ int part[4][CHUNK_];
  const int blk = blockIdx.x, b = blk >> 3, ch = blk & 7;
  const int bN = b * N_, t = threadIdx.x;
  sl[t]       = sc[bN + t];
  sl[t + 256] = sc[bN + t + 256];
  __syncthreads();
  const int n = t & 63, p = t >> 6;     // node-local, quarter
  const int g = ch * CHUNK_ + n;        // node's pre-sort index in batch
  const float my = sl[g];
  const float4* sl4 = (const float4*)sl;
  int rank = 0;
#pragma unroll 4
  for (int k4 = p * 32; k4 < p * 32 + 32; ++k4) {   // 128 compares per quarter
    float4 v = sl4[k4];                 // LDS broadcast across the wave
    int k = k4 * 4;
    rank += (int)((v.x > my) || (v.x == my && k     < g));
    rank += (int)((v.y > my) || (v.y == my && k + 1 < g));
    rank += (int)((v.z > my) || (v.z == my && k + 2 < g));
    rank += (int)((v.w > my) || (v.w == my && k + 3 < g));
  }
  part[p][n] = rank;
  __syncthreads();
  if (t < CHUNK_) {
    const int gg = ch * CHUNK_ + t;
    const int r = part[0][t] + part[1][t] + part[2][t] + part[3][t];
    order[bN + r] = gg;
    srk[bN + r]   = tanhf(sl[gg]);
  }
}

// ---------------- Kernel 3: LDS-staged window attention -------------------
// 512 blocks = 64 batches x 8 chunks of 64 r; 8 waves, 8 r per wave.
// asr/ads recomputed in-block from the staged rows (same f32 butterfly as
// the original k_scores -> bit-identical values). Proven in R13/R14.
__global__ __launch_bounds__(512) void k_att(
    const void* __restrict__ x, const void* __restrict__ a,
    const int* __restrict__ order, const int* __restrict__ ep,
    float* __restrict__ wrw, int* __restrict__ jmp)
{
  __shared__ float rows[MAXR_ * RSTRIDE_];   // 79*132*4 = 41712 B
  __shared__ float ads_l[MAXR_];
  __shared__ float asr_l[CHUNK_];
  __shared__ int   ord_l[MAXR_];
  __shared__ int   s_modes[2];
  __shared__ float s_invtau;

  const int blk = blockIdx.x;           // 64*8
  const int b = blk >> 3;
  const int cr0 = (blk & 7) * CHUNK_;
  const int bN = b * N_;
  const int t = threadIdx.x;            // 512 threads, 8 waves
  const int lane = t & 63, wv = t >> 6;
  const int nrows = min(N_ - cr0, MAXR_);

  if (t < 64) {
    int mx_ = detect_w0((const unsigned short*)x, lane);
    int ma_ = detect_w0((const unsigned short*)a, lane);
    if (t == 0) {
      s_modes[0] = mx_; s_modes[1] = ma_;
      float evv = get_epoch(ep);
      s_invtau = (float)(1.0 / (10.0 * pow(0.01, (double)evv / 100.0)));
    }
  }
  if (t < nrows) {
    int o = order[bN + cr0 + t];
    ord_l[t] = min(max(o, 0), N_ - 1);  // defensive clamp (no-op for valid data)
  }
  __syncthreads();
  const int mode_x = s_modes[0], mode_a = s_modes[1];
  const float inv_tau = s_invtau;

  // stage rows: 16 rows in flight, 32 threads x float4 per row (coalesced)
  {
    const int rl0 = t >> 5, c4 = t & 31;
    for (int rl = rl0; rl < nrows; rl += 16) {
      float4 v = ld4(x, (bN + ord_l[rl]) * 32 + c4, mode_x);
      float* dst = &rows[rl * RSTRIDE_ + c4 * 4];
      dst[0] = v.x; dst[1] = v.y; dst[2] = v.z; dst[3] = v.w;
    }
  }
  __syncthreads();

  // asr/ads from staged rows: lane covers channels 2*lane, 2*lane+1
  {
    const float2 sv2 = ld2(a, lane, mode_a);
    const float2 dv2 = ld2(a, 64 + lane, mode_a);
    for (int rl = wv; rl < nrows; rl += 8) {
      const float2 xr = *(const float2*)&rows[rl * RSTRIDE_ + 2 * lane];
      float da = wredf(xr.x * sv2.x + xr.y * sv2.y);
      float dd = wredf(xr.x * dv2.x + xr.y * dv2.y);
      if (lane == 0) {
        ads_l[rl] = dd;
        if (rl < CHUNK_) asr_l[rl] = da;
      }
    }
  }
  __syncthreads();

  const int j = lane & 15, cg4 = lane >> 4;
  const int nr = min(CHUNK_, RES_ - cr0);         // valid r in this chunk
  int cnt = nr - wv * 8; cnt = max(0, min(8, cnt));

#pragma unroll 2
  for (int ii = 0; ii < cnt; ++ii) {
    const int rloc = wv * 8 + ii;
    const int r = cr0 + rloc;
    const int dest = r + j;
    const bool valid = dest < N_;
    const int dl = (valid ? dest : (N_ - 1)) - cr0;

    const float* srcp = &rows[rloc * RSTRIDE_ + cg4 * 32];
    const float* dstp = &rows[dl   * RSTRIDE_ + cg4 * 32];
    // 4 partial f64 accumulators (dep chain 8); same order since R11.
    double p0 = 0.0, p1 = 0.0, p2 = 0.0, p3 = 0.0;
#pragma unroll
    for (int c = 0; c < 8; ++c) {
      float4 s4 = *(const float4*)(srcp + c * 4);
      float4 d4 = *(const float4*)(dstp + c * 4);
      float e0 = s4.x - d4.x, e1 = s4.y - d4.y;   // f32 subtract, like np
      float e2 = s4.z - d4.z, e3 = s4.w - d4.w;
      float q0 = e0 * e0, q1 = e1 * e1, q2 = e2 * e2, q3 = e3 * e3;
      p0 += (double)q0; p1 += (double)q1; p2 += (double)q2; p3 += (double)q3;
    }
    double dacc = (p0 + p1) + (p2 + p3);
    dacc += __shfl_xor(dacc, 16, 64);   // reduce channel quarters
    dacc += __shfl_xor(dacc, 32, 64);

    float d32 = sqrtf((float)dacc);
    float kkj = valid ? (__expf(-0.5f * d32) - 1e-20f) : -1e-20f;
    float aaj = valid ? (asr_l[rloc] + ads_l[dl]) : -1e9f;
    float ttj = aaj * inv_tau;

    float mx = ttj;
#pragma unroll
    for (int m = 1; m < 16; m <<= 1) mx = fmaxf(mx, __shfl_xor(mx, m, 64));
    float eej = __expf(ttj - mx);
    float ssum = eej;
#pragma unroll
    for (int m = 1; m < 16; m <<= 1) ssum += __shfl_xor(ssum, m, 64);
    float q  = kkj * (eej * (1.0f / ssum));
    float qm = valid ? q : -1e9f;

    float qe = (j == 0) ? -INFINITY : qm;         // exclude j=0 for jumps
    float m1 = qe;
#pragma unroll
    for (int m = 1; m < 16; m <<= 1) m1 = fmaxf(m1, __shfl_xor(m1, m, 64));
    float q0v = __shfl(qm, lane & 48, 64);        // this group's j=0 value
    float wr = fmaxf(m1, q0v);                    // == max over all j (exact)
    unsigned long long mask = __ballot(qe == m1);
    int bj = __builtin_ctz((unsigned)(mask & 0xFFFEu));   // first argmax, j>=1

    if (lane == 0) {
      wrw[bN + r] = wr;
      jmp[bN + r] = bj;
    }
  }
}

// ---------------- Kernel 4: jump-chain pooling via pointer doubling -------
__global__ __launch_bounds__(512) void k_chain(
    const void* __restrict__ x, const float* __restrict__ wrw,
    const float* __restrict__ srk, const int* __restrict__ jmp,
    const int* __restrict__ order, float* __restrict__ out)
{
  __shared__ int   tab[9][N_];   // f^(2^k) jump tables, sentinel 511
  __shared__ int   ol[N_];
  __shared__ float wl[N_];
  __shared__ float sl2[N_];
  __shared__ float cl[N_];       // coeff list in path order
  __shared__ int   rl[N_];       // row-id list
  __shared__ int   Pcnt;
  __shared__ int   s_mode;

  const int b = blockIdx.x, t = threadIdx.x;     // 512 threads
  if (t < 64) {
    int mx_ = detect_w0((const unsigned short*)x, t);
    if (t == 0) s_mode = mx_;
  }

  ol[t] = min(max(order[b * N_ + t], 0), N_ - 1);  // defensive clamp
  if (t < RES_) {
    wl[t]  = wrw[b * N_ + t];
    sl2[t] = srk[b * N_ + t];
    int jv = jmp[b * N_ + t];
    jv = min(max(jv, 1), FS_ - 1);                 // defensive clamp (jmp in [1,15])
    tab[0][t] = min(t + jv, RES_);
  } else {
    tab[0][t] = RES_;
  }
  if (t == 0) Pcnt = RES_;
  __syncthreads();
  const int mode_x = s_mode;
#pragma unroll
  for (int k = 1; k < 9; ++k) {
    int v = tab[k - 1][tab[k - 1][t]];
    tab[k][t] = v;
    __syncthreads();
  }
  int node = 0;
#pragma unroll
  for (int k = 0; k < 9; ++k)
    if ((t >> k) & 1) node = tab[k][node];
  bool valid = (node < RES_);
  cl[t] = valid ? wl[node] * sl2[node] : 0.0f;
  rl[t] = valid ? ol[node] : 0;
  if (!valid) atomicMin(&Pcnt, t);
  __syncthreads();

  if (t < C_) {
    const int P = Pcnt;
    float acc = 0.f;
    int i = 0;
    for (; i + 4 <= P; i += 4) {
      float c0 = cl[i],     c1 = cl[i + 1], c2 = cl[i + 2], c3 = cl[i + 3];
      int   r0 = rl[i],     r1 = rl[i + 1], r2 = rl[i + 2], r3 = rl[i + 3];
      float x0 = ld1(x, (b * N_ + r0) * C_ + t, mode_x);
      float x1 = ld1(x, (b * N_ + r1) * C_ + t, mode_x);
      float x2 = ld1(x, (b * N_ + r2) * C_ + t, mode_x);
      float x3 = ld1(x, (b * N_ + r3) * C_ + t, mode_x);
      acc = acc + c0 * x0;                       // exact reference order
      acc = acc + c1 * x1;
      acc = acc + c2 * x2;
      acc = acc + c3 * x3;
    }
    for (; i < P; ++i)
      acc = acc + cl[i] * ld1(x, (b * N_ + rl[i]) * C_ + t, mode_x);
    out[b * C_ + t] = acc;
  }
}

extern "C" void kernel_launch(void* const* d_in, const int* in_sizes, int n_in,
                              void* d_out, int out_size, void* d_ws, size_t ws_size,
                              hipStream_t stream) {
  const void* x = nullptr; const void* w = nullptr; const void* a = nullptr;
  const int* ep = nullptr;
  for (int i = 0; i < n_in; ++i) {
    int s = in_sizes[i];
    if      (s == B_ * N_ * C_) x  = d_in[i];
    else if (s == C_)           w  = d_in[i];
    else if (s == 2 * C_)       a  = d_in[i];
    else if (s == 1)            ep = (const int*)d_in[i];
  }
  if (!x)  x  = d_in[0];
  if (!w)  w  = d_in[2];
  if (!a)  a  = d_in[3];
  if (!ep) ep = (const int*)d_in[4];
  (void)out_size; (void)ws_size;

  float* ws = (float*)d_ws;
  const int NN = B_ * N_;              // 32768
  float* sc    = ws;                   // NN
  int*   order = (int*)(ws + NN);      // NN
  float* srk   = ws + 2 * NN;          // NN
  float* wrw   = ws + 3 * NN;          // NN
  int*   jmp   = (int*)(ws + 4 * NN);  // NN

  k_scores<<<NN / 4, 256, 0, stream>>>(x, w, sc);
  k_sort<<<B_ * 8, 256, 0, stream>>>(sc, order, srk);
  k_att<<<B_ * 8, 512, 0, stream>>>(x, a, order, ep, wrw, jmp);
  k_chain<<<B_, N_, 0, stream>>>(x, wrw, srk, jmp, order, (float*)d_out);
}